// Round 5
// baseline (406.838 us; speedup 1.0000x reference)
//
#include <hip/hip_runtime.h>
#include <math.h>

#define NN 8192
#define FIN 128
#define FOUT 64
#define LRELU 0.2f
#define JSPLIT 32
#define JCH (NN / JSPLIT)   // 256
#define HTSTR 264           // halfs; word-stride 132 = 4 mod 32 -> balanced banks
#define PSTRH 264           // p-tile row stride in halfs (528 B, 16B-aligned rows)
#define L2E 1.44269504f

typedef _Float16 f16x8 __attribute__((ext_vector_type(8)));
typedef _Float16 f16x4 __attribute__((ext_vector_type(4)));
typedef float f32x4 __attribute__((ext_vector_type(4)));

// workspace layout (float offsets)
#define WS_HT 0                        // H^T as f16 [FOUT][NN] = 262144 floats
#define WS_S1 262144
#define WS_S2 270336
#define WS_S2MAX 278528
#define WS_PACC 278544                 // JSPLIT x NN x FOUT f32 partials (67 MB)
#define WS_LP (WS_PACC + JSPLIT * NN * FOUT)

// ---------------------------------------------------------------------------
// Kernel 1: h = x@W; emit s1=h@a1, s2=h@a2 (f32) and H^T (f16, [feat][row]).
// ---------------------------------------------------------------------------
__global__ __launch_bounds__(256) void k_hs(const float* __restrict__ x,
                                            const float* __restrict__ W,
                                            const float* __restrict__ a,
                                            float* ws) {
  __shared__ float Wl[FIN * FOUT];   // 32 KB
  __shared__ float xl[16 * FIN];     // 8 KB
  __shared__ float hl[16 * FOUT];    // 4 KB
  const int t = threadIdx.x;
  const int i0 = blockIdx.x * 16;

#pragma unroll
  for (int c = 0; c < 8; ++c) {
    const int flat = c * 1024 + t * 4;
    *(float4*)&Wl[flat] = *(const float4*)&W[flat];
  }
#pragma unroll
  for (int c = 0; c < 2; ++c) {
    const int flat = c * 1024 + t * 4;
    *(float4*)&xl[flat] = *(const float4*)&x[(size_t)i0 * FIN + flat];
  }
  __syncthreads();

  const int r = t >> 4;     // local row 0..15
  const int fg = t & 15;    // feat group: feats [4*fg, 4*fg+4)
  float4 acc = make_float4(0.f, 0.f, 0.f, 0.f);
#pragma unroll 4
  for (int k = 0; k < FIN; ++k) {
    const float xv = xl[r * FIN + k];
    const float4 wv = *(const float4*)&Wl[k * FOUT + fg * 4];
    acc.x = fmaf(xv, wv.x, acc.x);
    acc.y = fmaf(xv, wv.y, acc.y);
    acc.z = fmaf(xv, wv.z, acc.z);
    acc.w = fmaf(xv, wv.w, acc.w);
  }

  float v1 = acc.x * a[fg * 4] + acc.y * a[fg * 4 + 1] +
             acc.z * a[fg * 4 + 2] + acc.w * a[fg * 4 + 3];
  float v2 = acc.x * a[FOUT + fg * 4] + acc.y * a[FOUT + fg * 4 + 1] +
             acc.z * a[FOUT + fg * 4 + 2] + acc.w * a[FOUT + fg * 4 + 3];
  v1 += __shfl_xor(v1, 1); v2 += __shfl_xor(v2, 1);
  v1 += __shfl_xor(v1, 2); v2 += __shfl_xor(v2, 2);
  v1 += __shfl_xor(v1, 4); v2 += __shfl_xor(v2, 4);
  v1 += __shfl_xor(v1, 8); v2 += __shfl_xor(v2, 8);
  if (fg == 0) {
    ws[WS_S1 + i0 + r] = v1;
    ws[WS_S2 + i0 + r] = v2;
  }

  // transpose h tile -> H^T (f16) via LDS
  *(float4*)&hl[r * FOUT + fg * 4] = acc;
  __syncthreads();
  _Float16* ht = (_Float16*)(ws + WS_HT);
  if (t < 128) {
    const int f = t >> 1;
    const int off = (t & 1) * 8;
    f16x8 tmp;
#pragma unroll
    for (int u = 0; u < 8; ++u) tmp[u] = (_Float16)hl[(off + u) * FOUT + f];
    *(f16x8*)&ht[(size_t)f * NN + i0 + off] = tmp;
  }
}

// ---------------------------------------------------------------------------
// Kernel 2: S2max = max_j s2[j]  (leaky monotone -> closed-form row max)
// ---------------------------------------------------------------------------
__global__ __launch_bounds__(256) void k_s2max(float* ws) {
  __shared__ float red[256];
  const int t = threadIdx.x;
  float v = -1e30f;
#pragma unroll
  for (int i = 0; i < NN / 256; ++i) v = fmaxf(v, ws[WS_S2 + i * 256 + t]);
  red[t] = v;
  __syncthreads();
  for (int s = 128; s >= 1; s >>= 1) {
    if (t < s) red[t] = fmaxf(red[t], red[t + s]);
    __syncthreads();
  }
  if (t == 0) ws[WS_S2MAX] = red[0];
}

// ---------------------------------------------------------------------------
// Kernel 3: contiguous-stream staging + MFMA.
// Grid: 128 i-bands x 32 j-splits = 4096 blocks, 256 thr (4 waves).
// Staging: wave w, step s (16 steps): lanes read ONE full 256-col row-chunk
//   of adj as a contiguous 1 KB wave-inst; compute p = adj?exp(leaky-m):0
//   (s1/m wave-uniform per step, s2 = one reused float4 per lane) and write
//   the f16 p-tile to LDS in MFMA-A row layout.
// Compute: one barrier, then pure ds_read_b128 A/B frags + MFMA + lacc.
// LDS = 33.3 KB p + 33 KB ht -> 2 blocks/CU.
// ---------------------------------------------------------------------------
__global__ __launch_bounds__(256, 2) void k_main(const int* __restrict__ adj,
                                                 float* ws) {
  __shared__ __align__(16) _Float16 pal[64 * PSTRH];    // 33792 B
  __shared__ __align__(16) _Float16 htl[FOUT * HTSTR];  // 33792 B

  const int t = threadIdx.x;
  const int ib = blockIdx.x >> 5;
  const int js = blockIdx.x & 31;
  const int i0 = ib * 64;
  const int jc0 = js * JCH;

  const _Float16* ht = (const _Float16*)(ws + WS_HT);

  // stage H^T chunk: 64 feats x 256 halfs, coalesced 16B
#pragma unroll
  for (int c = 0; c < 8; ++c) {
    const int chunk = c * 256 + t;      // 0..2047
    const int f = chunk >> 5;
    const int off = (chunk & 31) * 8;
    *(f16x8*)&htl[f * HTSTR + off] = *(const f16x8*)&ht[(size_t)f * NN + jc0 + off];
  }

  const int w = t >> 6;     // wave 0..3
  const int l = t & 63;
  const float s2max = ws[WS_S2MAX];
  // lane-private s2 quad, reused for all 16 staging steps
  const float4 s2v = *(const float4*)&ws[WS_S2 + jc0 + l * 4];

  // staging: 16 steps, one full row-chunk (1 KB contiguous) per wave-inst
#pragma unroll
  for (int s = 0; s < 16; ++s) {
    const int rl = w * 16 + s;                  // local row
    const float s1v = ws[WS_S1 + i0 + rl];      // wave-uniform
    const float tm = s1v + s2max;
    const float mv = fmaxf(tm, LRELU * tm);
    const float mneg = -mv * L2E;
    const int4 av = *(const int4*)&adj[(size_t)(i0 + rl) * NN + jc0 + l * 4];
    float e;
    e = s1v + s2v.x; e = fmaxf(e, LRELU * e);
    const _Float16 p0 = av.x ? (_Float16)exp2f(fmaf(e, L2E, mneg)) : (_Float16)0.f;
    e = s1v + s2v.y; e = fmaxf(e, LRELU * e);
    const _Float16 p1 = av.y ? (_Float16)exp2f(fmaf(e, L2E, mneg)) : (_Float16)0.f;
    e = s1v + s2v.z; e = fmaxf(e, LRELU * e);
    const _Float16 p2 = av.z ? (_Float16)exp2f(fmaf(e, L2E, mneg)) : (_Float16)0.f;
    e = s1v + s2v.w; e = fmaxf(e, LRELU * e);
    const _Float16 p3 = av.w ? (_Float16)exp2f(fmaf(e, L2E, mneg)) : (_Float16)0.f;
    f16x4 pv = {p0, p1, p2, p3};
    *(f16x4*)&pal[rl * PSTRH + l * 4] = pv;
  }

  __syncthreads();   // the only barrier

  const int m16 = l & 15;
  const int q8 = (l >> 4) * 8;

  f32x4 acc[4];
#pragma unroll
  for (int nf = 0; nf < 4; ++nf) acc[nf] = (f32x4){0.f, 0.f, 0.f, 0.f};
  float lacc = 0.f;

#pragma unroll
  for (int it = 0; it < JCH / 32; ++it) {   // 8 k-steps
    const int kb = it * 32 + q8;
    const f16x8 af = *(const f16x8*)&pal[(w * 16 + m16) * PSTRH + kb];
    // denominator from the f16-rounded p: cancels rounding in the ratio
#pragma unroll
    for (int u = 0; u < 8; ++u) lacc += (float)af[u];
#pragma unroll
    for (int nf = 0; nf < 4; ++nf) {
      const f16x8 b = *(const f16x8*)&htl[(nf * 16 + m16) * HTSTR + kb];
      acc[nf] = __builtin_amdgcn_mfma_f32_16x16x32_f16(af, b, acc[nf], 0, 0, 0);
    }
  }

  // row-sum partial: reduce lacc across the 4 quads (same m16)
  lacc += __shfl_xor(lacc, 16);
  lacc += __shfl_xor(lacc, 32);
  if (l < 16) ws[WS_LP + js * NN + i0 + w * 16 + m16] = lacc;

  // acc partials: C/D layout col=lane&15, row=(lane>>4)*4+reg
  float* pacc = ws + WS_PACC + (size_t)js * (NN * FOUT);
  const int orow = i0 + w * 16 + (l >> 4) * 4;
#pragma unroll
  for (int nf = 0; nf < 4; ++nf)
#pragma unroll
    for (int r = 0; r < 4; ++r)
      pacc[(size_t)(orow + r) * FOUT + nf * 16 + m16] = acc[nf][r];
}

// ---------------------------------------------------------------------------
// Kernel 4: combine j-split partials, normalize, ELU
// ---------------------------------------------------------------------------
__global__ __launch_bounds__(256) void k_combine(const float* __restrict__ ws,
                                                 float* __restrict__ out) {
  const int idx = blockIdx.x * 256 + threadIdx.x;
  const int i = idx >> 6;
  float s = 0.f, l = 0.f;
#pragma unroll
  for (int js = 0; js < JSPLIT; ++js) {
    s += ws[WS_PACC + (size_t)js * (NN * FOUT) + idx];
    l += ws[WS_LP + js * NN + i];
  }
  const float v = s / l;
  out[idx] = v > 0.f ? v : expm1f(v);
}

// ---------------------------------------------------------------------------
extern "C" void kernel_launch(void* const* d_in, const int* in_sizes, int n_in,
                              void* d_out, int out_size, void* d_ws,
                              size_t ws_size, hipStream_t stream) {
  const float* x = (const float*)d_in[0];
  const int* adj = (const int*)d_in[1];
  const float* W = (const float*)d_in[2];
  const float* a = (const float*)d_in[3];
  float* ws = (float*)d_ws;
  float* out = (float*)d_out;

  hipLaunchKernelGGL(k_hs, dim3(NN / 16), dim3(256), 0, stream, x, W, a, ws);
  hipLaunchKernelGGL(k_s2max, dim3(1), dim3(256), 0, stream, ws);
  hipLaunchKernelGGL(k_main, dim3((NN / 64) * JSPLIT), dim3(256), 0, stream,
                     adj, ws);
  hipLaunchKernelGGL(k_combine, dim3(NN * FOUT / 256), dim3(256), 0, stream,
                     ws, out);
}

// Round 6
// 388.977 us; speedup vs baseline: 1.0459x; 1.0459x over previous
//
#include <hip/hip_runtime.h>
#include <math.h>

#define NN 8192
#define FIN 128
#define FOUT 64
#define LRELU 0.2f
#define JSPLIT 32
#define JCH (NN / JSPLIT)   // 256
#define HTSTR 264           // halfs; word-stride 132 = 4 mod 32 -> balanced banks
#define L2E 1.44269504f

typedef _Float16 f16x8 __attribute__((ext_vector_type(8)));
typedef float f32x4 __attribute__((ext_vector_type(4)));

// workspace layout (float offsets)
#define WS_HT 0                        // H^T as f16 [FOUT][NN] = 262144 floats
#define WS_S1 262144
#define WS_S2 270336
#define WS_S2MAX 278528
#define WS_PACC 278544                 // JSPLIT x NN x FOUT f32 partials (67 MB)
#define WS_LP (WS_PACC + JSPLIT * NN * FOUT)

// ---------------------------------------------------------------------------
// Kernel 1: h = x@W; emit s1=h@a1, s2=h@a2 (f32) and H^T (f16, [feat][row]).
// ---------------------------------------------------------------------------
__global__ __launch_bounds__(256) void k_hs(const float* __restrict__ x,
                                            const float* __restrict__ W,
                                            const float* __restrict__ a,
                                            float* ws) {
  __shared__ float Wl[FIN * FOUT];   // 32 KB
  __shared__ float xl[16 * FIN];     // 8 KB
  __shared__ float hl[16 * FOUT];    // 4 KB
  const int t = threadIdx.x;
  const int i0 = blockIdx.x * 16;

#pragma unroll
  for (int c = 0; c < 8; ++c) {
    const int flat = c * 1024 + t * 4;
    *(float4*)&Wl[flat] = *(const float4*)&W[flat];
  }
#pragma unroll
  for (int c = 0; c < 2; ++c) {
    const int flat = c * 1024 + t * 4;
    *(float4*)&xl[flat] = *(const float4*)&x[(size_t)i0 * FIN + flat];
  }
  __syncthreads();

  const int r = t >> 4;     // local row 0..15
  const int fg = t & 15;    // feat group: feats [4*fg, 4*fg+4)
  float4 acc = make_float4(0.f, 0.f, 0.f, 0.f);
#pragma unroll 4
  for (int k = 0; k < FIN; ++k) {
    const float xv = xl[r * FIN + k];
    const float4 wv = *(const float4*)&Wl[k * FOUT + fg * 4];
    acc.x = fmaf(xv, wv.x, acc.x);
    acc.y = fmaf(xv, wv.y, acc.y);
    acc.z = fmaf(xv, wv.z, acc.z);
    acc.w = fmaf(xv, wv.w, acc.w);
  }

  float v1 = acc.x * a[fg * 4] + acc.y * a[fg * 4 + 1] +
             acc.z * a[fg * 4 + 2] + acc.w * a[fg * 4 + 3];
  float v2 = acc.x * a[FOUT + fg * 4] + acc.y * a[FOUT + fg * 4 + 1] +
             acc.z * a[FOUT + fg * 4 + 2] + acc.w * a[FOUT + fg * 4 + 3];
  v1 += __shfl_xor(v1, 1); v2 += __shfl_xor(v2, 1);
  v1 += __shfl_xor(v1, 2); v2 += __shfl_xor(v2, 2);
  v1 += __shfl_xor(v1, 4); v2 += __shfl_xor(v2, 4);
  v1 += __shfl_xor(v1, 8); v2 += __shfl_xor(v2, 8);
  if (fg == 0) {
    ws[WS_S1 + i0 + r] = v1;
    ws[WS_S2 + i0 + r] = v2;
  }

  // transpose h tile -> H^T (f16) via LDS
  *(float4*)&hl[r * FOUT + fg * 4] = acc;
  __syncthreads();
  _Float16* ht = (_Float16*)(ws + WS_HT);
  if (t < 128) {
    const int f = t >> 1;
    const int off = (t & 1) * 8;
    f16x8 tmp;
#pragma unroll
    for (int u = 0; u < 8; ++u) tmp[u] = (_Float16)hl[(off + u) * FOUT + f];
    *(f16x8*)&ht[(size_t)f * NN + i0 + off] = tmp;
  }
}

// ---------------------------------------------------------------------------
// Kernel 2: S2max = max_j s2[j]  (leaky monotone -> closed-form row max)
// ---------------------------------------------------------------------------
__global__ __launch_bounds__(256) void k_s2max(float* ws) {
  __shared__ float red[256];
  const int t = threadIdx.x;
  float v = -1e30f;
#pragma unroll
  for (int i = 0; i < NN / 256; ++i) v = fmaxf(v, ws[WS_S2 + i * 256 + t]);
  red[t] = v;
  __syncthreads();
  for (int s = 128; s >= 1; s >>= 1) {
    if (t < s) red[t] = fmaxf(red[t], red[t + s]);
    __syncthreads();
  }
  if (t == 0) ws[WS_S2MAX] = red[0];
}

// ---------------------------------------------------------------------------
// Kernel 3: burst-prefetch streaming pass (MLP-forced).
// Grid: 128 i-bands x 32 j-splits = 4096 blocks, 256 thr (4 waves).
// Each wave: 16-row band x 256 cols. ALL 16 adj int4 loads issued as one
// burst into registers (64 VGPRs, 14+ loads in flight at first consume),
// then 8 k-steps: p in registers (MFMA-A layout), B-frags from LDS ht.
// No pal LDS; LDS = 33.8 KB ht + 1 KB s2 -> 4 blocks/CU = 16 waves/CU.
// ---------------------------------------------------------------------------
__global__ __launch_bounds__(256, 4) void k_main(const int* __restrict__ adj,
                                                 float* ws) {
  __shared__ __align__(16) _Float16 htl[FOUT * HTSTR];  // 33792 B
  __shared__ float s2l[JCH];                            // 1 KB

  const int t = threadIdx.x;
  const int ib = blockIdx.x >> 5;
  const int js = blockIdx.x & 31;
  const int i0 = ib * 64;
  const int jc0 = js * JCH;

  const _Float16* ht = (const _Float16*)(ws + WS_HT);

  // stage H^T chunk: 64 feats x 256 halfs, coalesced 16B
#pragma unroll
  for (int c = 0; c < 8; ++c) {
    const int chunk = c * 256 + t;      // 0..2047
    const int f = chunk >> 5;
    const int off = (chunk & 31) * 8;
    *(f16x8*)&htl[f * HTSTR + off] = *(const f16x8*)&ht[(size_t)f * NN + jc0 + off];
  }
  s2l[t] = ws[WS_S2 + jc0 + t];   // JCH == blockDim == 256

  const int w = t >> 6;     // wave 0..3
  const int l = t & 63;
  const int m16 = l & 15;
  const int q8 = (l >> 4) * 8;
  const int row = i0 + w * 16 + m16;

  const float s2max = ws[WS_S2MAX];
  const float s1v = ws[WS_S1 + row];
  const float tmp0 = s1v + s2max;
  const float mv = fmaxf(tmp0, LRELU * tmp0);
  const float mneg = -mv * L2E;

  const int* arow = adj + (size_t)row * NN + jc0 + q8;

  // ---- burst: issue ALL 16 independent int4 loads before any consume ----
  int4 av[16];
#pragma unroll
  for (int u = 0; u < 16; ++u)
    av[u] = *(const int4*)(arow + (u >> 1) * 32 + (u & 1) * 4);

  f32x4 acc[4];
#pragma unroll
  for (int nf = 0; nf < 4; ++nf) acc[nf] = (f32x4){0.f, 0.f, 0.f, 0.f};
  float lacc = 0.f;

  __syncthreads();   // the only barrier

#pragma unroll
  for (int it = 0; it < JCH / 32; ++it) {   // 8 k-steps
    const int4 a0 = av[2 * it];
    const int4 a1 = av[2 * it + 1];
    const float4 s20 = *(const float4*)&s2l[it * 32 + q8];
    const float4 s21 = *(const float4*)&s2l[it * 32 + q8 + 4];

    float e, p[8];
    e = s1v + s20.x; e = fmaxf(e, LRELU * e); p[0] = a0.x ? exp2f(fmaf(e, L2E, mneg)) : 0.f;
    e = s1v + s20.y; e = fmaxf(e, LRELU * e); p[1] = a0.y ? exp2f(fmaf(e, L2E, mneg)) : 0.f;
    e = s1v + s20.z; e = fmaxf(e, LRELU * e); p[2] = a0.z ? exp2f(fmaf(e, L2E, mneg)) : 0.f;
    e = s1v + s20.w; e = fmaxf(e, LRELU * e); p[3] = a0.w ? exp2f(fmaf(e, L2E, mneg)) : 0.f;
    e = s1v + s21.x; e = fmaxf(e, LRELU * e); p[4] = a1.x ? exp2f(fmaf(e, L2E, mneg)) : 0.f;
    e = s1v + s21.y; e = fmaxf(e, LRELU * e); p[5] = a1.y ? exp2f(fmaf(e, L2E, mneg)) : 0.f;
    e = s1v + s21.z; e = fmaxf(e, LRELU * e); p[6] = a1.z ? exp2f(fmaf(e, L2E, mneg)) : 0.f;
    e = s1v + s21.w; e = fmaxf(e, LRELU * e); p[7] = a1.w ? exp2f(fmaf(e, L2E, mneg)) : 0.f;

    f16x8 af;
#pragma unroll
    for (int u = 0; u < 8; ++u) af[u] = (_Float16)p[u];
    // denominator from the f16-rounded p: cancels rounding in the ratio
#pragma unroll
    for (int u = 0; u < 8; ++u) lacc += (float)af[u];

    const int kb = it * 32 + q8;
#pragma unroll
    for (int nf = 0; nf < 4; ++nf) {
      const f16x8 b = *(const f16x8*)&htl[(nf * 16 + m16) * HTSTR + kb];
      acc[nf] = __builtin_amdgcn_mfma_f32_16x16x32_f16(af, b, acc[nf], 0, 0, 0);
    }
  }

  // row-sum partial: reduce lacc across the 4 quads (same m16)
  lacc += __shfl_xor(lacc, 16);
  lacc += __shfl_xor(lacc, 32);
  if (l < 16) ws[WS_LP + js * NN + row] = lacc;

  // acc partials: C/D layout col=lane&15, row=(lane>>4)*4+reg
  float* pacc = ws + WS_PACC + (size_t)js * (NN * FOUT);
  const int orow = i0 + w * 16 + (l >> 4) * 4;
#pragma unroll
  for (int nf = 0; nf < 4; ++nf)
#pragma unroll
    for (int r = 0; r < 4; ++r)
      pacc[(size_t)(orow + r) * FOUT + nf * 16 + m16] = acc[nf][r];
}

// ---------------------------------------------------------------------------
// Kernel 4: combine j-split partials, normalize, ELU
// ---------------------------------------------------------------------------
__global__ __launch_bounds__(256) void k_combine(const float* __restrict__ ws,
                                                 float* __restrict__ out) {
  const int idx = blockIdx.x * 256 + threadIdx.x;
  const int i = idx >> 6;
  float s = 0.f, l = 0.f;
#pragma unroll
  for (int js = 0; js < JSPLIT; ++js) {
    s += ws[WS_PACC + (size_t)js * (NN * FOUT) + idx];
    l += ws[WS_LP + js * NN + i];
  }
  const float v = s / l;
  out[idx] = v > 0.f ? v : expm1f(v);
}

// ---------------------------------------------------------------------------
extern "C" void kernel_launch(void* const* d_in, const int* in_sizes, int n_in,
                              void* d_out, int out_size, void* d_ws,
                              size_t ws_size, hipStream_t stream) {
  const float* x = (const float*)d_in[0];
  const int* adj = (const int*)d_in[1];
  const float* W = (const float*)d_in[2];
  const float* a = (const float*)d_in[3];
  float* ws = (float*)d_ws;
  float* out = (float*)d_out;

  hipLaunchKernelGGL(k_hs, dim3(NN / 16), dim3(256), 0, stream, x, W, a, ws);
  hipLaunchKernelGGL(k_s2max, dim3(1), dim3(256), 0, stream, ws);
  hipLaunchKernelGGL(k_main, dim3((NN / 64) * JSPLIT), dim3(256), 0, stream,
                     adj, ws);
  hipLaunchKernelGGL(k_combine, dim3(NN * FOUT / 256), dim3(256), 0, stream,
                     ws, out);
}

// Round 7
// 380.695 us; speedup vs baseline: 1.0687x; 1.0218x over previous
//
#include <hip/hip_runtime.h>
#include <math.h>

#define NN 8192
#define FIN 128
#define FOUT 64
#define LRELU 0.2f
#define JSPLIT 16
#define JCH (NN / JSPLIT)   // 512
#define HTSTR 520           // halfs; word-stride 260 = 4 mod 32 -> balanced banks
#define L2E 1.44269504f

typedef _Float16 f16x8 __attribute__((ext_vector_type(8)));
typedef float f32x4 __attribute__((ext_vector_type(4)));
typedef int i32x4 __attribute__((ext_vector_type(4)));

// workspace layout (float offsets)
#define WS_HT 0                        // H^T as f16 [FOUT][NN] = 262144 floats
#define WS_S1 262144
#define WS_S2 270336
#define WS_S2MAX 278528
#define WS_PACC 278544                 // JSPLIT x NN x FOUT f32 partials (34 MB)
#define WS_LP (WS_PACC + JSPLIT * NN * FOUT)

// ---------------------------------------------------------------------------
// Kernel 1: h = x@W; emit s1=h@a1, s2=h@a2 (f32) and H^T (f16, [feat][row]).
// ---------------------------------------------------------------------------
__global__ __launch_bounds__(256) void k_hs(const float* __restrict__ x,
                                            const float* __restrict__ W,
                                            const float* __restrict__ a,
                                            float* ws) {
  __shared__ float Wl[FIN * FOUT];   // 32 KB
  __shared__ float xl[16 * FIN];     // 8 KB
  __shared__ float hl[16 * FOUT];    // 4 KB
  const int t = threadIdx.x;
  const int i0 = blockIdx.x * 16;

#pragma unroll
  for (int c = 0; c < 8; ++c) {
    const int flat = c * 1024 + t * 4;
    *(float4*)&Wl[flat] = *(const float4*)&W[flat];
  }
#pragma unroll
  for (int c = 0; c < 2; ++c) {
    const int flat = c * 1024 + t * 4;
    *(float4*)&xl[flat] = *(const float4*)&x[(size_t)i0 * FIN + flat];
  }
  __syncthreads();

  const int r = t >> 4;     // local row 0..15
  const int fg = t & 15;    // feat group: feats [4*fg, 4*fg+4)
  float4 acc = make_float4(0.f, 0.f, 0.f, 0.f);
#pragma unroll 4
  for (int k = 0; k < FIN; ++k) {
    const float xv = xl[r * FIN + k];
    const float4 wv = *(const float4*)&Wl[k * FOUT + fg * 4];
    acc.x = fmaf(xv, wv.x, acc.x);
    acc.y = fmaf(xv, wv.y, acc.y);
    acc.z = fmaf(xv, wv.z, acc.z);
    acc.w = fmaf(xv, wv.w, acc.w);
  }

  float v1 = acc.x * a[fg * 4] + acc.y * a[fg * 4 + 1] +
             acc.z * a[fg * 4 + 2] + acc.w * a[fg * 4 + 3];
  float v2 = acc.x * a[FOUT + fg * 4] + acc.y * a[FOUT + fg * 4 + 1] +
             acc.z * a[FOUT + fg * 4 + 2] + acc.w * a[FOUT + fg * 4 + 3];
  v1 += __shfl_xor(v1, 1); v2 += __shfl_xor(v2, 1);
  v1 += __shfl_xor(v1, 2); v2 += __shfl_xor(v2, 2);
  v1 += __shfl_xor(v1, 4); v2 += __shfl_xor(v2, 4);
  v1 += __shfl_xor(v1, 8); v2 += __shfl_xor(v2, 8);
  if (fg == 0) {
    ws[WS_S1 + i0 + r] = v1;
    ws[WS_S2 + i0 + r] = v2;
  }

  // transpose h tile -> H^T (f16) via LDS
  *(float4*)&hl[r * FOUT + fg * 4] = acc;
  __syncthreads();
  _Float16* ht = (_Float16*)(ws + WS_HT);
  if (t < 128) {
    const int f = t >> 1;
    const int off = (t & 1) * 8;
    f16x8 tmp;
#pragma unroll
    for (int u = 0; u < 8; ++u) tmp[u] = (_Float16)hl[(off + u) * FOUT + f];
    *(f16x8*)&ht[(size_t)f * NN + i0 + off] = tmp;
  }
}

// ---------------------------------------------------------------------------
// Kernel 2: S2max = max_j s2[j]  (leaky monotone -> closed-form row max)
// ---------------------------------------------------------------------------
__global__ __launch_bounds__(256) void k_s2max(float* ws) {
  __shared__ float red[256];
  const int t = threadIdx.x;
  float v = -1e30f;
#pragma unroll
  for (int i = 0; i < NN / 256; ++i) v = fmaxf(v, ws[WS_S2 + i * 256 + t]);
  red[t] = v;
  __syncthreads();
  for (int s = 128; s >= 1; s >>= 1) {
    if (t < s) red[t] = fmaxf(red[t], red[t + s]);
    __syncthreads();
  }
  if (t == 0) ws[WS_S2MAX] = red[0];
}

// ---------------------------------------------------------------------------
// Kernel 3: full-depth burst streaming pass (uncapped VGPR, nontemporal).
// Grid: 128 i-bands x 16 j-splits = 2048 blocks, 256 thr (4 waves), 2 blk/CU.
// Each lane bursts its ENTIRE 512-col row chunk: 32 independent nt int4
// loads (128 VGPRs, all in flight before first consume), then 16 k-steps:
// p in registers (MFMA-A layout), B-frags from LDS ht. No VGPR cap.
// LDS = 65 KB ht + 2 KB s2 -> 2 blocks/CU = 8 waves/CU.
// ---------------------------------------------------------------------------
__global__ __launch_bounds__(256, 2) void k_main(const int* __restrict__ adj,
                                                 float* ws) {
  __shared__ __align__(16) _Float16 htl[FOUT * HTSTR];  // 66560 B
  __shared__ float s2l[JCH];                            // 2 KB

  const int t = threadIdx.x;
  const int ib = blockIdx.x >> 4;
  const int js = blockIdx.x & 15;
  const int i0 = ib * 64;
  const int jc0 = js * JCH;

  const _Float16* ht = (const _Float16*)(ws + WS_HT);

  // stage H^T chunk: 64 feats x 512 halfs, coalesced 16B
#pragma unroll
  for (int c = 0; c < 16; ++c) {
    const int chunk = c * 256 + t;      // 0..4095
    const int f = chunk >> 6;
    const int off = (chunk & 63) * 8;
    *(f16x8*)&htl[f * HTSTR + off] = *(const f16x8*)&ht[(size_t)f * NN + jc0 + off];
  }
  s2l[t] = ws[WS_S2 + jc0 + t];
  s2l[t + 256] = ws[WS_S2 + jc0 + t + 256];

  const int w = t >> 6;     // wave 0..3
  const int l = t & 63;
  const int m16 = l & 15;
  const int q8 = (l >> 4) * 8;
  const int row = i0 + w * 16 + m16;

  const float s2max = ws[WS_S2MAX];
  const float s1v = ws[WS_S1 + row];
  const float tmp0 = s1v + s2max;
  const float mv = fmaxf(tmp0, LRELU * tmp0);
  const float mneg = -mv * L2E;

  const int* arow = adj + (size_t)row * NN + jc0 + q8;

  __syncthreads();   // before the burst: no vmcnt drain can split it

  // ---- burst: ALL 32 independent nt int4 loads before any consume ----
  i32x4 av[32];
#pragma unroll
  for (int u = 0; u < 32; ++u)
    av[u] = __builtin_nontemporal_load(
        (const i32x4*)(arow + (u >> 1) * 32 + (u & 1) * 4));

  f32x4 acc[4];
#pragma unroll
  for (int nf = 0; nf < 4; ++nf) acc[nf] = (f32x4){0.f, 0.f, 0.f, 0.f};
  float lacc = 0.f;

#pragma unroll
  for (int it = 0; it < JCH / 32; ++it) {   // 16 k-steps
    const i32x4 a0 = av[2 * it];
    const i32x4 a1 = av[2 * it + 1];
    const float4 s20 = *(const float4*)&s2l[it * 32 + q8];
    const float4 s21 = *(const float4*)&s2l[it * 32 + q8 + 4];

    float e, p[8];
    e = s1v + s20.x; e = fmaxf(e, LRELU * e); p[0] = a0.x ? exp2f(fmaf(e, L2E, mneg)) : 0.f;
    e = s1v + s20.y; e = fmaxf(e, LRELU * e); p[1] = a0.y ? exp2f(fmaf(e, L2E, mneg)) : 0.f;
    e = s1v + s20.z; e = fmaxf(e, LRELU * e); p[2] = a0.z ? exp2f(fmaf(e, L2E, mneg)) : 0.f;
    e = s1v + s20.w; e = fmaxf(e, LRELU * e); p[3] = a0.w ? exp2f(fmaf(e, L2E, mneg)) : 0.f;
    e = s1v + s21.x; e = fmaxf(e, LRELU * e); p[4] = a1.x ? exp2f(fmaf(e, L2E, mneg)) : 0.f;
    e = s1v + s21.y; e = fmaxf(e, LRELU * e); p[5] = a1.y ? exp2f(fmaf(e, L2E, mneg)) : 0.f;
    e = s1v + s21.z; e = fmaxf(e, LRELU * e); p[6] = a1.z ? exp2f(fmaf(e, L2E, mneg)) : 0.f;
    e = s1v + s21.w; e = fmaxf(e, LRELU * e); p[7] = a1.w ? exp2f(fmaf(e, L2E, mneg)) : 0.f;

    f16x8 af;
#pragma unroll
    for (int u = 0; u < 8; ++u) af[u] = (_Float16)p[u];
    // denominator from the f16-rounded p: cancels rounding in the ratio
#pragma unroll
    for (int u = 0; u < 8; ++u) lacc += (float)af[u];

    const int kb = it * 32 + q8;
#pragma unroll
    for (int nf = 0; nf < 4; ++nf) {
      const f16x8 b = *(const f16x8*)&htl[(nf * 16 + m16) * HTSTR + kb];
      acc[nf] = __builtin_amdgcn_mfma_f32_16x16x32_f16(af, b, acc[nf], 0, 0, 0);
    }
  }

  // row-sum partial: reduce lacc across the 4 quads (same m16)
  lacc += __shfl_xor(lacc, 16);
  lacc += __shfl_xor(lacc, 32);
  if (l < 16) ws[WS_LP + js * NN + row] = lacc;

  // acc partials: C/D layout col=lane&15, row=(lane>>4)*4+reg; nt stores
  float* pacc = ws + WS_PACC + (size_t)js * (NN * FOUT);
  const int orow = i0 + w * 16 + (l >> 4) * 4;
#pragma unroll
  for (int nf = 0; nf < 4; ++nf)
#pragma unroll
    for (int r = 0; r < 4; ++r)
      __builtin_nontemporal_store(
          acc[nf][r], &pacc[(size_t)(orow + r) * FOUT + nf * 16 + m16]);
}

// ---------------------------------------------------------------------------
// Kernel 4: combine j-split partials, normalize, ELU
// ---------------------------------------------------------------------------
__global__ __launch_bounds__(256) void k_combine(const float* __restrict__ ws,
                                                 float* __restrict__ out) {
  const int idx = blockIdx.x * 256 + threadIdx.x;
  const int i = idx >> 6;
  float s = 0.f, l = 0.f;
#pragma unroll
  for (int js = 0; js < JSPLIT; ++js) {
    s += ws[WS_PACC + (size_t)js * (NN * FOUT) + idx];
    l += ws[WS_LP + js * NN + i];
  }
  const float v = s / l;
  out[idx] = v > 0.f ? v : expm1f(v);
}

// ---------------------------------------------------------------------------
extern "C" void kernel_launch(void* const* d_in, const int* in_sizes, int n_in,
                              void* d_out, int out_size, void* d_ws,
                              size_t ws_size, hipStream_t stream) {
  const float* x = (const float*)d_in[0];
  const int* adj = (const int*)d_in[1];
  const float* W = (const float*)d_in[2];
  const float* a = (const float*)d_in[3];
  float* ws = (float*)d_ws;
  float* out = (float*)d_out;

  hipLaunchKernelGGL(k_hs, dim3(NN / 16), dim3(256), 0, stream, x, W, a, ws);
  hipLaunchKernelGGL(k_s2max, dim3(1), dim3(256), 0, stream, ws);
  hipLaunchKernelGGL(k_main, dim3((NN / 64) * JSPLIT), dim3(256), 0, stream,
                     adj, ws);
  hipLaunchKernelGGL(k_combine, dim3(NN * FOUT / 256), dim3(256), 0, stream,
                     ws, out);
}